// Round 18
// baseline (4295.914 us; speedup 1.0000x reference)
//
#include <hip/hip_runtime.h>
#include <hip/hip_bf16.h>

#define BB 128
#define SS 1000
#define II 128
#define HH 1024
#define G4 4096
#define KK (II + HH)   // 1152
#define NC 50
#define NB 256         // persistent blocks (8 groups x 32)
#define SPIN_LIM (1 << 20)

typedef __attribute__((ext_vector_type(8))) short short8v;
typedef __attribute__((ext_vector_type(4))) float f32x4;

#define MF(A, B, C) __builtin_amdgcn_mfma_f32_16x16x32_bf16((A), (B), (C), 0, 0, 0)

static __device__ __forceinline__ unsigned f2bfu(float f) {
    union { float f; unsigned u; } v; v.f = f;
    unsigned u = v.u;
    u += 0x7FFFu + ((u >> 16) & 1u);   // RNE
    return u >> 16;
}
static __device__ __forceinline__ short f2bf(float f) { return (short)f2bfu(f); }

// pack 8 f32 -> 8 bf16 (RNE, identical to f2bf) via v_cvt_pk_bf16_f32
static __device__ __forceinline__ short8v pack8(f32x4 a, f32x4 b) {
    union { short8v s; unsigned u[4]; } cv;
    asm("v_cvt_pk_bf16_f32 %0, %1, %2" : "=v"(cv.u[0]) : "v"(a[0]), "v"(a[1]));
    asm("v_cvt_pk_bf16_f32 %0, %1, %2" : "=v"(cv.u[1]) : "v"(a[2]), "v"(a[3]));
    asm("v_cvt_pk_bf16_f32 %0, %1, %2" : "=v"(cv.u[2]) : "v"(b[0]), "v"(b[1]));
    asm("v_cvt_pk_bf16_f32 %0, %1, %2" : "=v"(cv.u[3]) : "v"(b[2]), "v"(b[3]));
    return cv.s;
}

// ---------------------------------------------------------------------------
// Weight prep: Bt[n][k] (bf16, n = gate*1024 + j, k in [0,1152)) from fp32.
// grid (36, 32, 4), block (32, 8)
// ---------------------------------------------------------------------------
__global__ void prep_weights(const float* __restrict__ Wx0, const float* __restrict__ Wx1,
                             const float* __restrict__ Wx2, const float* __restrict__ Wx3,
                             const float* __restrict__ Wh0, const float* __restrict__ Wh1,
                             const float* __restrict__ Wh2, const float* __restrict__ Wh3,
                             short* __restrict__ Bt) {
    __shared__ float lds[32][33];
    const int kt = blockIdx.x, jt = blockIdx.y, g = blockIdx.z;
    const int tx = threadIdx.x, ty = threadIdx.y;
    const float* Wx = (g == 0) ? Wx0 : (g == 1) ? Wx1 : (g == 2) ? Wx2 : Wx3;
    const float* Wh = (g == 0) ? Wh0 : (g == 1) ? Wh1 : (g == 2) ? Wh2 : Wh3;
    const int k0 = kt * 32, j0 = jt * 32;
#pragma unroll
    for (int r = 0; r < 4; r++) {
        int kk = k0 + ty + r * 8;
        float v = (kk < II) ? Wx[kk * HH + j0 + tx] : Wh[(kk - II) * HH + j0 + tx];
        lds[ty + r * 8][tx] = v;
    }
    __syncthreads();
#pragma unroll
    for (int r = 0; r < 4; r++) {
        int jj = ty + r * 8;
        Bt[(size_t)(g * HH + j0 + jj) * KK + k0 + tx] = f2bf(lds[tx][jj]);
    }
}

// ---------------------------------------------------------------------------
// Pack bias [4096]; zero hbuf[0]; zero flags. grid 512, block 256.
// ---------------------------------------------------------------------------
__global__ void prep_misc(const float* __restrict__ bi, const float* __restrict__ bf_,
                          const float* __restrict__ bg, const float* __restrict__ bo,
                          float* __restrict__ b4, short* __restrict__ hbuf,
                          unsigned* __restrict__ flags) {
    int i = blockIdx.x * 256 + threadIdx.x;
    if (i < G4) {
        float v = (i < HH) ? bi[i] : (i < 2 * HH) ? bf_[i - HH]
                : (i < 3 * HH) ? bg[i - 2 * HH] : bo[i - 3 * HH];
        b4[i] = v;
    }
    if (i < BB * HH) hbuf[i] = 0;   // h(0) = 0 in buffer 0
    if (i < 1024) flags[i] = 0;     // barrier flags (8 groups x 64 slots)
}

// ---------------------------------------------------------------------------
// Persistent LSTM. 256 blocks x 256 threads, bid-based groups (mg = bid&7,
// jg = bid>>3). PURE agent-scope protocol (r6/r17-proven class: all memory
// ops compiler-tracked, all barriers uniform __syncthreads). NEW vs r17:
// the h(t) exchange is split into two 16KB column-chunks keyed to producer
// halves — chunk1's poll+flight overlaps chunk0's staging+MFMA. Same flag
// protocol, same buffer-parity proof (both chunk polls complete before the
// elementwise, so flag>=t+1 still implies the peer finished reading h(t)).
// ---------------------------------------------------------------------------
__global__ __launch_bounds__(256, 1) void lstm_persist(
    const float* __restrict__ x, const short* __restrict__ Bt,
    const float* __restrict__ b4, short* __restrict__ hbuf,
    float* __restrict__ hf, unsigned* __restrict__ flags) {
    const int bid = blockIdx.x;
    const int mg = bid & 7, jg = bid >> 3;
    const int m0 = mg * 16, j0 = jg * 32;
    const int tid = threadIdx.x;
    const int g = tid >> 6, l = tid & 63;
    const int lq = l >> 4, lr = l & 15;
    unsigned* gflags = flags + mg * 64;      // this group's flag line

    __shared__ __align__(16) short hstage[16 * 1024];   // 2KB rows, XOR-swizzled
    __shared__ float g4s[4][16][33];
    __shared__ float c_lds[16][33];
    __shared__ int dead;

    if (tid == 0) dead = 0;
    for (int i = tid; i < 16 * 33; i += 256) ((float*)c_lds)[i] = 0.f;

    // --- this wave's weight slice -> registers (once) ---
    short8v Bw[36][2];
    {
        const short* Bg = Bt + (size_t)(g * HH + j0) * KK;
#pragma unroll
        for (int kk = 0; kk < 36; kk++) {
#pragma unroll
            for (int nt = 0; nt < 2; nt++) {
                Bw[kk][nt] = *(const short8v*)(Bg + (size_t)(nt * 16 + lr) * KK + kk * 32 + lq * 8);
            }
        }
    }

    const int arow = m0 + lr;                       // A-operand batch row
    const float* xrow = x + (size_t)arow * SS * II;

    // staging decomposition: thread -> (rowA = tid>>7 base, col word c8)
    const int srow = tid >> 7;        // 0/1: which row of each q-pair
    const int c8 = tid & 127;         // column word within 128-ull half-row

    // elementwise constants: thread -> (m_e, cols j2, j2+1)
    const int m_e = tid >> 4;            // 0..15
    const int j2 = (tid & 15) * 2;       // 0..30
    const float bi0 = b4[j0 + j2],          bi1 = b4[j0 + j2 + 1];
    const float bf0 = b4[HH + j0 + j2],     bf1 = b4[HH + j0 + j2 + 1];
    const float bg0 = b4[2 * HH + j0 + j2], bg1 = b4[2 * HH + j0 + j2 + 1];
    const float bo0 = b4[3 * HH + j0 + j2], bo1 = b4[3 * HH + j0 + j2 + 1];

    __syncthreads();

    // 4 accumulator chains: (nt 0/1) x (even/odd k-tile)
    f32x4 a0a = {0.f, 0.f, 0.f, 0.f}, a0b = a0a, a1a = a0a, a1b = a0a;
    f32x4 xr[8];   // x(t+1) prefetch registers

    // prologue: x-part of step 0 (direct loads)
#pragma unroll
    for (int kk = 0; kk < 4; kk++) {
        const f32x4* xp = (const f32x4*)(xrow + kk * 32 + lq * 8);
        short8v a_ = pack8(xp[0], xp[1]);
        if (kk & 1) { a0b = MF(a_, Bw[kk][0], a0b); a1b = MF(a_, Bw[kk][1], a1b); }
        else        { a0a = MF(a_, Bw[kk][0], a0a); a1a = MF(a_, Bw[kk][1], a1a); }
    }

    for (int t = 0; t < SS; t++) {
        const short* hcur = hbuf + (size_t)(t & 1) * (BB * HH);
        short* hnxt = hbuf + (size_t)((t + 1) & 1) * (BB * HH);
        const unsigned e = (unsigned)t;
        const unsigned long long* hsrc =
            (const unsigned long long*)(hcur + (size_t)m0 * HH);

        // 1a. wait for chunk0 of h(t): producers jg 0..15 (k-cols 0..511)
        if (!dead && tid < 16) {
            int it = 0;
            while (__hip_atomic_load(&gflags[tid], __ATOMIC_RELAXED,
                                     __HIP_MEMORY_SCOPE_AGENT) < e) {
                if (++it > SPIN_LIM) { dead = 1; break; }
            }
        }
        __syncthreads();

        // 1b. issue chunk0 loads (rows 2q+srow, col words 0..127)
        unsigned long long v0[8];
#pragma unroll
        for (int q = 0; q < 8; q++)
            v0[q] = __hip_atomic_load(hsrc + (size_t)(2 * q + srow) * 256 + c8,
                                      __ATOMIC_RELAXED, __HIP_MEMORY_SCOPE_AGENT);

        // 1c. wait for chunk1 (producers jg 16..31) — overlaps chunk0 flight
        if (!dead && tid >= 16 && tid < 32) {
            int it = 0;
            while (__hip_atomic_load(&gflags[tid], __ATOMIC_RELAXED,
                                     __HIP_MEMORY_SCOPE_AGENT) < e) {
                if (++it > SPIN_LIM) { dead = 1; break; }
            }
        }
        __syncthreads();

        // 1d. issue chunk1 loads (col words 128..255), then write chunk0 to
        //     LDS (compiler's counted wait drains only v0; v1 stays in flight)
        unsigned long long v1[8];
#pragma unroll
        for (int q = 0; q < 8; q++)
            v1[q] = __hip_atomic_load(hsrc + (size_t)(2 * q + srow) * 256 + 128 + c8,
                                      __ATOMIC_RELAXED, __HIP_MEMORY_SCOPE_AGENT);
#pragma unroll
        for (int q = 0; q < 8; q++) {
            const int row = 2 * q + srow;
            const int off = (c8 * 8) ^ ((row & 7) << 4);
            *(unsigned long long*)((char*)hstage + row * 2048 + off) = v0[q];
        }
        __syncthreads();   // chunk0 staged

        // 2a. MFMA k-tiles 4..19 (chunk0) — chunk1 loads still in flight
#pragma unroll
        for (int kk2 = 0; kk2 < 16; kk2++) {
            short8v a_ = *(const short8v*)((const char*)hstage + lr * 2048 +
                                           ((kk2 * 64 + lq * 16) ^ ((lr & 7) << 4)));
            if (kk2 & 1) { a0b = MF(a_, Bw[kk2 + 4][0], a0b); a1b = MF(a_, Bw[kk2 + 4][1], a1b); }
            else         { a0a = MF(a_, Bw[kk2 + 4][0], a0a); a1a = MF(a_, Bw[kk2 + 4][1], a1a); }
        }

        // 2b. write chunk1 to LDS (waits v1), barrier, MFMA k-tiles 20..35
#pragma unroll
        for (int q = 0; q < 8; q++) {
            const int row = 2 * q + srow;
            const int off = ((128 + c8) * 8) ^ ((row & 7) << 4);
            *(unsigned long long*)((char*)hstage + row * 2048 + off) = v1[q];
        }
        __syncthreads();   // chunk1 staged
#pragma unroll
        for (int kk2 = 16; kk2 < 32; kk2++) {
            short8v a_ = *(const short8v*)((const char*)hstage + lr * 2048 +
                                           ((kk2 * 64 + lq * 16) ^ ((lr & 7) << 4)));
            if (kk2 & 1) { a0b = MF(a_, Bw[kk2 + 4][0], a0b); a1b = MF(a_, Bw[kk2 + 4][1], a1b); }
            else         { a0a = MF(a_, Bw[kk2 + 4][0], a0a); a1a = MF(a_, Bw[kk2 + 4][1], a1a); }
        }

        // 3. gates -> LDS   (C/D map: col = lane&15, row = lq*4 + r)
#pragma unroll
        for (int r = 0; r < 4; r++) {
            g4s[g][lq * 4 + r][lr]      = a0a[r] + a0b[r];
            g4s[g][lq * 4 + r][16 + lr] = a1a[r] + a1b[r];
        }
        __syncthreads();

        // 4. elementwise + h(t+1) store (relaxed agent atomic, tracked)
        {
            float gi0 = g4s[0][m_e][j2] + bi0, gi1 = g4s[0][m_e][j2 + 1] + bi1;
            float gf0 = g4s[1][m_e][j2] + bf0, gf1 = g4s[1][m_e][j2 + 1] + bf1;
            float gg0 = g4s[2][m_e][j2] + bg0, gg1 = g4s[2][m_e][j2 + 1] + bg1;
            float go0 = g4s[3][m_e][j2] + bo0, go1 = g4s[3][m_e][j2 + 1] + bo1;
            float si0 = 1.f / (1.f + __expf(-gi0)), si1 = 1.f / (1.f + __expf(-gi1));
            float sf0 = 1.f / (1.f + __expf(-gf0)), sf1 = 1.f / (1.f + __expf(-gf1));
            float tg0 = 1.f - 2.f / (__expf(2.f * gg0) + 1.f);
            float tg1 = 1.f - 2.f / (__expf(2.f * gg1) + 1.f);
            float so0 = 1.f / (1.f + __expf(-go0)), so1 = 1.f / (1.f + __expf(-go1));
            float cn0 = sf0 * c_lds[m_e][j2] + si0 * tg0;
            float cn1 = sf1 * c_lds[m_e][j2 + 1] + si1 * tg1;
            c_lds[m_e][j2] = cn0;
            c_lds[m_e][j2 + 1] = cn1;
            float h0 = so0 * (1.f - 2.f / (__expf(2.f * cn0) + 1.f));
            float h1 = so1 * (1.f - 2.f / (__expf(2.f * cn1) + 1.f));
            unsigned pv = f2bfu(h0) | (f2bfu(h1) << 16);
            unsigned* hp = (unsigned*)(hnxt + (size_t)(m0 + m_e) * HH + j0 + j2);
            __hip_atomic_store(hp, pv, __ATOMIC_RELAXED, __HIP_MEMORY_SCOPE_AGENT);
            if (t == SS - 1) {
                *(float2*)(hf + (size_t)(m0 + m_e) * HH + j0 + j2) = make_float2(h0, h1);
            }
        }

        if (t == SS - 1) break;

        // 4b. issue x(t+1) prefetch loads (h-independent, compiler-tracked;
        //     drain together with the h-stores at the barrier below)
        {
            const float* xt = xrow + (size_t)(t + 1) * II;
#pragma unroll
            for (int kk = 0; kk < 4; kk++) {
                xr[2 * kk]     = *(const f32x4*)(xt + kk * 32 + lq * 8);
                xr[2 * kk + 1] = *(const f32x4*)(xt + kk * 32 + lq * 8 + 4);
            }
        }

        // 5. publish h(t+1): __syncthreads drains all waves' tracked stores
        //    (vmcnt(0) before s_barrier), then relaxed flag store.
        __syncthreads();
        if (!dead && tid == 0)
            __hip_atomic_store(&gflags[jg], (unsigned)(t + 1),
                               __ATOMIC_RELAXED, __HIP_MEMORY_SCOPE_AGENT);

        // 6. x-part of step t+1 from prefetched registers
        a0a = f32x4{0.f, 0.f, 0.f, 0.f}; a0b = a0a; a1a = a0a; a1b = a0a;
#pragma unroll
        for (int kk = 0; kk < 4; kk++) {
            short8v a_ = pack8(xr[2 * kk], xr[2 * kk + 1]);
            if (kk & 1) { a0b = MF(a_, Bw[kk][0], a0b); a1b = MF(a_, Bw[kk][1], a1b); }
            else        { a0a = MF(a_, Bw[kk][0], a0a); a1a = MF(a_, Bw[kk][1], a1a); }
        }
    }

    (void)dead;
}

// ---------------------------------------------------------------------------
// out[b][o] = h[b] . W_out[o] + b_out[o].  grid 128 (b), block 256.
// ---------------------------------------------------------------------------
__global__ void final_linear(const float* __restrict__ hf, const float* __restrict__ Wout,
                             const float* __restrict__ bout, float* __restrict__ out) {
    __shared__ float hs[HH];
    const int b = blockIdx.x;
    for (int i = threadIdx.x; i < HH; i += 256) hs[i] = hf[(size_t)b * HH + i];
    __syncthreads();
    const int w = threadIdx.x >> 6, l = threadIdx.x & 63;
    for (int o = w; o < NC; o += 4) {
        float s = 0.f;
        const float* wr = Wout + (size_t)o * HH;
        for (int jj = l; jj < HH; jj += 64) s += hs[jj] * wr[jj];
#pragma unroll
        for (int d = 32; d > 0; d >>= 1) s += __shfl_down(s, d);
        if (l == 0) out[b * NC + o] = s + bout[o];
    }
}

extern "C" void kernel_launch(void* const* d_in, const int* in_sizes, int n_in,
                              void* d_out, int out_size, void* d_ws, size_t ws_size,
                              hipStream_t stream) {
    const float* x    = (const float*)d_in[0];
    const float* W_ii = (const float*)d_in[1];
    const float* W_hi = (const float*)d_in[2];
    const float* b_ii = (const float*)d_in[3];
    const float* W_if = (const float*)d_in[4];
    const float* W_hf = (const float*)d_in[5];
    const float* b_if = (const float*)d_in[6];
    const float* W_ig = (const float*)d_in[7];
    const float* W_hg = (const float*)d_in[8];
    const float* b_ig = (const float*)d_in[9];
    const float* W_io = (const float*)d_in[10];
    const float* W_ho = (const float*)d_in[11];
    const float* b_io = (const float*)d_in[12];
    const float* W_out = (const float*)d_in[13];
    const float* b_out = (const float*)d_in[14];

    char* ws = (char*)d_ws;
    short* Bt   = (short*)ws;                                  // 9,437,184 B
    float* b4   = (float*)(ws + 9437184);                      // 16,384 B
    short* hbuf = (short*)(ws + 9437184 + 16384);              // 524,288 B
    float* hf   = (float*)(ws + 9437184 + 16384 + 524288);     // 524,288 B
    unsigned* flags = (unsigned*)(ws + 9437184 + 16384 + 524288 + 524288); // 4,096 B

    prep_weights<<<dim3(36, 32, 4), dim3(32, 8), 0, stream>>>(
        W_ii, W_if, W_ig, W_io, W_hi, W_hf, W_hg, W_ho, Bt);
    prep_misc<<<512, 256, 0, stream>>>(b_ii, b_if, b_ig, b_io, b4, hbuf, flags);

    lstm_persist<<<NB, 256, 0, stream>>>(x, Bt, b4, hbuf, hf, flags);

    final_linear<<<BB, 256, 0, stream>>>(hf, W_out, b_out, (float*)d_out);
}

// Round 19
// 4135.290 us; speedup vs baseline: 1.0388x; 1.0388x over previous
//
#include <hip/hip_runtime.h>
#include <hip/hip_bf16.h>

#define BB 128
#define SS 1000
#define II 128
#define HH 1024
#define G4 4096
#define KK (II + HH)   // 1152
#define NC 50
#define NB 256         // persistent blocks (8 groups x 32)
#define SPIN_LIM (1 << 20)

typedef __attribute__((ext_vector_type(8))) short short8v;
typedef __attribute__((ext_vector_type(4))) float f32x4;

#define MF(A, B, C) __builtin_amdgcn_mfma_f32_16x16x32_bf16((A), (B), (C), 0, 0, 0)

static __device__ __forceinline__ unsigned f2bfu(float f) {
    union { float f; unsigned u; } v; v.f = f;
    unsigned u = v.u;
    u += 0x7FFFu + ((u >> 16) & 1u);   // RNE
    return u >> 16;
}
static __device__ __forceinline__ short f2bf(float f) { return (short)f2bfu(f); }

// pack 8 f32 -> 8 bf16 (RNE, identical to f2bf) via v_cvt_pk_bf16_f32
static __device__ __forceinline__ short8v pack8(f32x4 a, f32x4 b) {
    union { short8v s; unsigned u[4]; } cv;
    asm("v_cvt_pk_bf16_f32 %0, %1, %2" : "=v"(cv.u[0]) : "v"(a[0]), "v"(a[1]));
    asm("v_cvt_pk_bf16_f32 %0, %1, %2" : "=v"(cv.u[1]) : "v"(a[2]), "v"(a[3]));
    asm("v_cvt_pk_bf16_f32 %0, %1, %2" : "=v"(cv.u[2]) : "v"(b[0]), "v"(b[1]));
    asm("v_cvt_pk_bf16_f32 %0, %1, %2" : "=v"(cv.u[3]) : "v"(b[2]), "v"(b[3]));
    return cv.s;
}

// ---------------------------------------------------------------------------
// Weight prep: Bt[n][k] (bf16, n = gate*1024 + j, k in [0,1152)) from fp32.
// grid (36, 32, 4), block (32, 8)
// ---------------------------------------------------------------------------
__global__ void prep_weights(const float* __restrict__ Wx0, const float* __restrict__ Wx1,
                             const float* __restrict__ Wx2, const float* __restrict__ Wx3,
                             const float* __restrict__ Wh0, const float* __restrict__ Wh1,
                             const float* __restrict__ Wh2, const float* __restrict__ Wh3,
                             short* __restrict__ Bt) {
    __shared__ float lds[32][33];
    const int kt = blockIdx.x, jt = blockIdx.y, g = blockIdx.z;
    const int tx = threadIdx.x, ty = threadIdx.y;
    const float* Wx = (g == 0) ? Wx0 : (g == 1) ? Wx1 : (g == 2) ? Wx2 : Wx3;
    const float* Wh = (g == 0) ? Wh0 : (g == 1) ? Wh1 : (g == 2) ? Wh2 : Wh3;
    const int k0 = kt * 32, j0 = jt * 32;
#pragma unroll
    for (int r = 0; r < 4; r++) {
        int kk = k0 + ty + r * 8;
        float v = (kk < II) ? Wx[kk * HH + j0 + tx] : Wh[(kk - II) * HH + j0 + tx];
        lds[ty + r * 8][tx] = v;
    }
    __syncthreads();
#pragma unroll
    for (int r = 0; r < 4; r++) {
        int jj = ty + r * 8;
        Bt[(size_t)(g * HH + j0 + jj) * KK + k0 + tx] = f2bf(lds[tx][jj]);
    }
}

// ---------------------------------------------------------------------------
// Pack bias [4096]; zero hbuf[0]; zero flags. grid 512, block 256.
// ---------------------------------------------------------------------------
__global__ void prep_misc(const float* __restrict__ bi, const float* __restrict__ bf_,
                          const float* __restrict__ bg, const float* __restrict__ bo,
                          float* __restrict__ b4, short* __restrict__ hbuf,
                          unsigned* __restrict__ flags) {
    int i = blockIdx.x * 256 + threadIdx.x;
    if (i < G4) {
        float v = (i < HH) ? bi[i] : (i < 2 * HH) ? bf_[i - HH]
                : (i < 3 * HH) ? bg[i - 2 * HH] : bo[i - 3 * HH];
        b4[i] = v;
    }
    if (i < BB * HH) hbuf[i] = 0;   // h(0) = 0 in buffer 0
    if (i < 1024) flags[i] = 0;     // barrier flags (8 groups x 64 slots)
}

// ---------------------------------------------------------------------------
// Persistent LSTM. 256 blocks x 256 threads, bid-based groups (mg = bid&7,
// jg = bid>>3). PURE agent-scope protocol (r6/r17-proven class: all memory
// ops compiler-tracked, all barriers uniform __syncthreads). NEW vs r17:
// poll and stage are MERGED — staging thread tid's 16 words (word column tid
// of rows 0..15) are all produced by group-peer jg' = tid>>3, so each thread
// polls exactly its producer's flag and then issues its own loads (pure
// per-thread dependency; in-order issue orders loads after the poll's branch
// resolves). This removes one full barrier+drain per step and parallelizes
// poll detection across 256 threads. 3 barriers/step instead of 4.
// ---------------------------------------------------------------------------
__global__ __launch_bounds__(256, 1) void lstm_persist(
    const float* __restrict__ x, const short* __restrict__ Bt,
    const float* __restrict__ b4, short* __restrict__ hbuf,
    float* __restrict__ hf, unsigned* __restrict__ flags) {
    const int bid = blockIdx.x;
    const int mg = bid & 7, jg = bid >> 3;
    const int m0 = mg * 16, j0 = jg * 32;
    const int tid = threadIdx.x;
    const int g = tid >> 6, l = tid & 63;
    const int lq = l >> 4, lr = l & 15;
    unsigned* gflags = flags + mg * 64;      // this group's flag line
    unsigned* myflag = &gflags[tid >> 3];    // producer of word column tid

    __shared__ __align__(16) short hstage[16 * 1024];   // 2KB rows, XOR-swizzled
    __shared__ float g4s[4][16][33];
    __shared__ float c_lds[16][33];
    __shared__ int dead;

    if (tid == 0) dead = 0;
    for (int i = tid; i < 16 * 33; i += 256) ((float*)c_lds)[i] = 0.f;

    // --- this wave's weight slice -> registers (once) ---
    short8v Bw[36][2];
    {
        const short* Bg = Bt + (size_t)(g * HH + j0) * KK;
#pragma unroll
        for (int kk = 0; kk < 36; kk++) {
#pragma unroll
            for (int nt = 0; nt < 2; nt++) {
                Bw[kk][nt] = *(const short8v*)(Bg + (size_t)(nt * 16 + lr) * KK + kk * 32 + lq * 8);
            }
        }
    }

    const int arow = m0 + lr;                       // A-operand batch row
    const float* xrow = x + (size_t)arow * SS * II;

    // elementwise constants: thread -> (m_e, cols j2, j2+1)
    const int m_e = tid >> 4;            // 0..15
    const int j2 = (tid & 15) * 2;       // 0..30
    const float bi0 = b4[j0 + j2],          bi1 = b4[j0 + j2 + 1];
    const float bf0 = b4[HH + j0 + j2],     bf1 = b4[HH + j0 + j2 + 1];
    const float bg0 = b4[2 * HH + j0 + j2], bg1 = b4[2 * HH + j0 + j2 + 1];
    const float bo0 = b4[3 * HH + j0 + j2], bo1 = b4[3 * HH + j0 + j2 + 1];

    __syncthreads();

    // 4 accumulator chains: (nt 0/1) x (even/odd k-tile)
    f32x4 a0a = {0.f, 0.f, 0.f, 0.f}, a0b = a0a, a1a = a0a, a1b = a0a;
    f32x4 xr[8];   // x(t+1) prefetch registers

    // prologue: x-part of step 0 (direct loads)
#pragma unroll
    for (int kk = 0; kk < 4; kk++) {
        const f32x4* xp = (const f32x4*)(xrow + kk * 32 + lq * 8);
        short8v a_ = pack8(xp[0], xp[1]);
        if (kk & 1) { a0b = MF(a_, Bw[kk][0], a0b); a1b = MF(a_, Bw[kk][1], a1b); }
        else        { a0a = MF(a_, Bw[kk][0], a0a); a1a = MF(a_, Bw[kk][1], a1a); }
    }

    for (int t = 0; t < SS; t++) {
        const short* hcur = hbuf + (size_t)(t & 1) * (BB * HH);
        short* hnxt = hbuf + (size_t)((t + 1) & 1) * (BB * HH);

        // 1. merged poll+stage: each thread polls ITS producer's flag, then
        //    loads its 16 words (word column tid of rows 0..15) and writes
        //    them to LDS with the XOR swizzle. One barrier merges all.
        {
            if (!dead) {
                const unsigned e = (unsigned)t;
                int it = 0;
                while (__hip_atomic_load(myflag, __ATOMIC_RELAXED,
                                         __HIP_MEMORY_SCOPE_AGENT) < e) {
                    if (++it > SPIN_LIM) { dead = 1; break; }
                }
            }
            const unsigned long long* hsrc =
                (const unsigned long long*)(hcur + (size_t)m0 * HH);
            unsigned long long v[16];
#pragma unroll
            for (int q = 0; q < 16; q++)
                v[q] = __hip_atomic_load(hsrc + q * 256 + tid,
                                         __ATOMIC_RELAXED, __HIP_MEMORY_SCOPE_AGENT);
#pragma unroll
            for (int q = 0; q < 16; q++) {
                int off = (tid * 8) ^ ((q & 7) << 4);
                *(unsigned long long*)((char*)hstage + q * 2048 + off) = v[q];
            }
        }
        __syncthreads();

        // 2. h-part MFMAs: A-fragments from swizzled LDS (4 chains)
#pragma unroll
        for (int kk2 = 0; kk2 < 32; kk2++) {
            short8v a_ = *(const short8v*)((const char*)hstage + lr * 2048 +
                                           ((kk2 * 64 + lq * 16) ^ ((lr & 7) << 4)));
            if (kk2 & 1) { a0b = MF(a_, Bw[kk2 + 4][0], a0b); a1b = MF(a_, Bw[kk2 + 4][1], a1b); }
            else         { a0a = MF(a_, Bw[kk2 + 4][0], a0a); a1a = MF(a_, Bw[kk2 + 4][1], a1a); }
        }

        // 3. gates -> LDS   (C/D map: col = lane&15, row = lq*4 + r)
#pragma unroll
        for (int r = 0; r < 4; r++) {
            g4s[g][lq * 4 + r][lr]      = a0a[r] + a0b[r];
            g4s[g][lq * 4 + r][16 + lr] = a1a[r] + a1b[r];
        }
        __syncthreads();

        // 4. elementwise + h(t+1) store (relaxed agent atomic, tracked)
        {
            float gi0 = g4s[0][m_e][j2] + bi0, gi1 = g4s[0][m_e][j2 + 1] + bi1;
            float gf0 = g4s[1][m_e][j2] + bf0, gf1 = g4s[1][m_e][j2 + 1] + bf1;
            float gg0 = g4s[2][m_e][j2] + bg0, gg1 = g4s[2][m_e][j2 + 1] + bg1;
            float go0 = g4s[3][m_e][j2] + bo0, go1 = g4s[3][m_e][j2 + 1] + bo1;
            float si0 = 1.f / (1.f + __expf(-gi0)), si1 = 1.f / (1.f + __expf(-gi1));
            float sf0 = 1.f / (1.f + __expf(-gf0)), sf1 = 1.f / (1.f + __expf(-gf1));
            float tg0 = 1.f - 2.f / (__expf(2.f * gg0) + 1.f);
            float tg1 = 1.f - 2.f / (__expf(2.f * gg1) + 1.f);
            float so0 = 1.f / (1.f + __expf(-go0)), so1 = 1.f / (1.f + __expf(-go1));
            float cn0 = sf0 * c_lds[m_e][j2] + si0 * tg0;
            float cn1 = sf1 * c_lds[m_e][j2 + 1] + si1 * tg1;
            c_lds[m_e][j2] = cn0;
            c_lds[m_e][j2 + 1] = cn1;
            float h0 = so0 * (1.f - 2.f / (__expf(2.f * cn0) + 1.f));
            float h1 = so1 * (1.f - 2.f / (__expf(2.f * cn1) + 1.f));
            unsigned pv = f2bfu(h0) | (f2bfu(h1) << 16);
            unsigned* hp = (unsigned*)(hnxt + (size_t)(m0 + m_e) * HH + j0 + j2);
            __hip_atomic_store(hp, pv, __ATOMIC_RELAXED, __HIP_MEMORY_SCOPE_AGENT);
            if (t == SS - 1) {
                *(float2*)(hf + (size_t)(m0 + m_e) * HH + j0 + j2) = make_float2(h0, h1);
            }
        }

        if (t == SS - 1) break;

        // 4b. issue x(t+1) prefetch loads (h-independent, compiler-tracked;
        //     drain together with the h-stores at the barrier below)
        {
            const float* xt = xrow + (size_t)(t + 1) * II;
#pragma unroll
            for (int kk = 0; kk < 4; kk++) {
                xr[2 * kk]     = *(const f32x4*)(xt + kk * 32 + lq * 8);
                xr[2 * kk + 1] = *(const f32x4*)(xt + kk * 32 + lq * 8 + 4);
            }
        }

        // 5. publish h(t+1): __syncthreads drains all waves' tracked stores
        //    (vmcnt(0) before s_barrier), then relaxed flag store.
        __syncthreads();
        if (!dead && tid == 0)
            __hip_atomic_store(&gflags[jg], (unsigned)(t + 1),
                               __ATOMIC_RELAXED, __HIP_MEMORY_SCOPE_AGENT);

        // 6. x-part of step t+1 from prefetched registers
        a0a = f32x4{0.f, 0.f, 0.f, 0.f}; a0b = a0a; a1a = a0a; a1b = a0a;
#pragma unroll
        for (int kk = 0; kk < 4; kk++) {
            short8v a_ = pack8(xr[2 * kk], xr[2 * kk + 1]);
            if (kk & 1) { a0b = MF(a_, Bw[kk][0], a0b); a1b = MF(a_, Bw[kk][1], a1b); }
            else        { a0a = MF(a_, Bw[kk][0], a0a); a1a = MF(a_, Bw[kk][1], a1a); }
        }
    }

    (void)dead;
}

// ---------------------------------------------------------------------------
// out[b][o] = h[b] . W_out[o] + b_out[o].  grid 128 (b), block 256.
// ---------------------------------------------------------------------------
__global__ void final_linear(const float* __restrict__ hf, const float* __restrict__ Wout,
                             const float* __restrict__ bout, float* __restrict__ out) {
    __shared__ float hs[HH];
    const int b = blockIdx.x;
    for (int i = threadIdx.x; i < HH; i += 256) hs[i] = hf[(size_t)b * HH + i];
    __syncthreads();
    const int w = threadIdx.x >> 6, l = threadIdx.x & 63;
    for (int o = w; o < NC; o += 4) {
        float s = 0.f;
        const float* wr = Wout + (size_t)o * HH;
        for (int jj = l; jj < HH; jj += 64) s += hs[jj] * wr[jj];
#pragma unroll
        for (int d = 32; d > 0; d >>= 1) s += __shfl_down(s, d);
        if (l == 0) out[b * NC + o] = s + bout[o];
    }
}

extern "C" void kernel_launch(void* const* d_in, const int* in_sizes, int n_in,
                              void* d_out, int out_size, void* d_ws, size_t ws_size,
                              hipStream_t stream) {
    const float* x    = (const float*)d_in[0];
    const float* W_ii = (const float*)d_in[1];
    const float* W_hi = (const float*)d_in[2];
    const float* b_ii = (const float*)d_in[3];
    const float* W_if = (const float*)d_in[4];
    const float* W_hf = (const float*)d_in[5];
    const float* b_if = (const float*)d_in[6];
    const float* W_ig = (const float*)d_in[7];
    const float* W_hg = (const float*)d_in[8];
    const float* b_ig = (const float*)d_in[9];
    const float* W_io = (const float*)d_in[10];
    const float* W_ho = (const float*)d_in[11];
    const float* b_io = (const float*)d_in[12];
    const float* W_out = (const float*)d_in[13];
    const float* b_out = (const float*)d_in[14];

    char* ws = (char*)d_ws;
    short* Bt   = (short*)ws;                                  // 9,437,184 B
    float* b4   = (float*)(ws + 9437184);                      // 16,384 B
    short* hbuf = (short*)(ws + 9437184 + 16384);              // 524,288 B
    float* hf   = (float*)(ws + 9437184 + 16384 + 524288);     // 524,288 B
    unsigned* flags = (unsigned*)(ws + 9437184 + 16384 + 524288 + 524288); // 4,096 B

    prep_weights<<<dim3(36, 32, 4), dim3(32, 8), 0, stream>>>(
        W_ii, W_if, W_ig, W_io, W_hi, W_hf, W_hg, W_ho, Bt);
    prep_misc<<<512, 256, 0, stream>>>(b_ii, b_if, b_ig, b_io, b4, hbuf, flags);

    lstm_persist<<<NB, 256, 0, stream>>>(x, Bt, b4, hbuf, hf, flags);

    final_linear<<<BB, 256, 0, stream>>>(hf, W_out, b_out, (float*)d_out);
}

// Round 21
// 4125.855 us; speedup vs baseline: 1.0412x; 1.0023x over previous
//
#include <hip/hip_runtime.h>
#include <hip/hip_bf16.h>

#define BB 128
#define SS 1000
#define II 128
#define HH 1024
#define G4 4096
#define KK (II + HH)   // 1152
#define NC 50
#define NB 256         // persistent blocks (8 groups x 32)
#define SPIN_LIM (1 << 20)

typedef __attribute__((ext_vector_type(8))) short short8v;
typedef __attribute__((ext_vector_type(4))) float f32x4;

#define MF(A, B, C) __builtin_amdgcn_mfma_f32_16x16x32_bf16((A), (B), (C), 0, 0, 0)

static __device__ __forceinline__ unsigned f2bfu(float f) {
    union { float f; unsigned u; } v; v.f = f;
    unsigned u = v.u;
    u += 0x7FFFu + ((u >> 16) & 1u);   // RNE
    return u >> 16;
}
static __device__ __forceinline__ short f2bf(float f) { return (short)f2bfu(f); }

// pack 8 f32 -> 8 bf16 (RNE, identical to f2bf) via v_cvt_pk_bf16_f32
static __device__ __forceinline__ short8v pack8(f32x4 a, f32x4 b) {
    union { short8v s; unsigned u[4]; } cv;
    asm("v_cvt_pk_bf16_f32 %0, %1, %2" : "=v"(cv.u[0]) : "v"(a[0]), "v"(a[1]));
    asm("v_cvt_pk_bf16_f32 %0, %1, %2" : "=v"(cv.u[1]) : "v"(a[2]), "v"(a[3]));
    asm("v_cvt_pk_bf16_f32 %0, %1, %2" : "=v"(cv.u[2]) : "v"(b[0]), "v"(b[1]));
    asm("v_cvt_pk_bf16_f32 %0, %1, %2" : "=v"(cv.u[3]) : "v"(b[2]), "v"(b[3]));
    return cv.s;
}

// ---------------------------------------------------------------------------
// Weight prep: Bt[n][k] (bf16, n = gate*1024 + j, k in [0,1152)) from fp32.
// grid (36, 32, 4), block (32, 8)
// ---------------------------------------------------------------------------
__global__ void prep_weights(const float* __restrict__ Wx0, const float* __restrict__ Wx1,
                             const float* __restrict__ Wx2, const float* __restrict__ Wx3,
                             const float* __restrict__ Wh0, const float* __restrict__ Wh1,
                             const float* __restrict__ Wh2, const float* __restrict__ Wh3,
                             short* __restrict__ Bt) {
    __shared__ float lds[32][33];
    const int kt = blockIdx.x, jt = blockIdx.y, g = blockIdx.z;
    const int tx = threadIdx.x, ty = threadIdx.y;
    const float* Wx = (g == 0) ? Wx0 : (g == 1) ? Wx1 : (g == 2) ? Wx2 : Wx3;
    const float* Wh = (g == 0) ? Wh0 : (g == 1) ? Wh1 : (g == 2) ? Wh2 : Wh3;
    const int k0 = kt * 32, j0 = jt * 32;
#pragma unroll
    for (int r = 0; r < 4; r++) {
        int kk = k0 + ty + r * 8;
        float v = (kk < II) ? Wx[kk * HH + j0 + tx] : Wh[(kk - II) * HH + j0 + tx];
        lds[ty + r * 8][tx] = v;
    }
    __syncthreads();
#pragma unroll
    for (int r = 0; r < 4; r++) {
        int jj = ty + r * 8;
        Bt[(size_t)(g * HH + j0 + jj) * KK + k0 + tx] = f2bf(lds[tx][jj]);
    }
}

// ---------------------------------------------------------------------------
// Pack bias [4096]; zero hbuf[0]; zero flags. grid 512, block 256.
// ---------------------------------------------------------------------------
__global__ void prep_misc(const float* __restrict__ bi, const float* __restrict__ bf_,
                          const float* __restrict__ bg, const float* __restrict__ bo,
                          float* __restrict__ b4, short* __restrict__ hbuf,
                          unsigned* __restrict__ flags) {
    int i = blockIdx.x * 256 + threadIdx.x;
    if (i < G4) {
        float v = (i < HH) ? bi[i] : (i < 2 * HH) ? bf_[i - HH]
                : (i < 3 * HH) ? bg[i - 2 * HH] : bo[i - 3 * HH];
        b4[i] = v;
    }
    if (i < BB * HH) hbuf[i] = 0;   // h(0) = 0 in buffer 0
    if (i < 1024) flags[i] = 0;     // barrier flags (8 groups x 64 slots)
}

// ---------------------------------------------------------------------------
// Persistent LSTM. 256 blocks x 256 threads, bid-based groups (mg = bid&7,
// jg = bid>>3). PURE agent-scope protocol (r6/r17-proven class: all memory
// ops compiler-tracked, all barriers uniform __syncthreads). Poll and stage
// are MERGED — staging thread tid's 16 words (word column tid of rows 0..15)
// are all produced by group-peer jg' = tid>>3, so each thread polls exactly
// its producer's flag and then issues its own loads (per-thread dependency;
// in-order issue orders loads after the poll's branch resolves). 3 barriers
// per step. Compute: pack8 conversion, 4 split accumulator chains, x(t+1)
// register prefetch.
// ---------------------------------------------------------------------------
__global__ __launch_bounds__(256, 1) void lstm_persist(
    const float* __restrict__ x, const short* __restrict__ Bt,
    const float* __restrict__ b4, short* __restrict__ hbuf,
    float* __restrict__ hf, unsigned* __restrict__ flags) {
    const int bid = blockIdx.x;
    const int mg = bid & 7, jg = bid >> 3;
    const int m0 = mg * 16, j0 = jg * 32;
    const int tid = threadIdx.x;
    const int g = tid >> 6, l = tid & 63;
    const int lq = l >> 4, lr = l & 15;
    unsigned* gflags = flags + mg * 64;      // this group's flag line
    unsigned* myflag = &gflags[tid >> 3];    // producer of word column tid

    __shared__ __align__(16) short hstage[16 * 1024];   // 2KB rows, XOR-swizzled
    __shared__ float g4s[4][16][33];
    __shared__ float c_lds[16][33];
    __shared__ int dead;

    if (tid == 0) dead = 0;
    for (int i = tid; i < 16 * 33; i += 256) ((float*)c_lds)[i] = 0.f;

    // --- this wave's weight slice -> registers (once) ---
    short8v Bw[36][2];
    {
        const short* Bg = Bt + (size_t)(g * HH + j0) * KK;
#pragma unroll
        for (int kk = 0; kk < 36; kk++) {
#pragma unroll
            for (int nt = 0; nt < 2; nt++) {
                Bw[kk][nt] = *(const short8v*)(Bg + (size_t)(nt * 16 + lr) * KK + kk * 32 + lq * 8);
            }
        }
    }

    const int arow = m0 + lr;                       // A-operand batch row
    const float* xrow = x + (size_t)arow * SS * II;

    // elementwise constants: thread -> (m_e, cols j2, j2+1)
    const int m_e = tid >> 4;            // 0..15
    const int j2 = (tid & 15) * 2;       // 0..30
    const float bi0 = b4[j0 + j2],          bi1 = b4[j0 + j2 + 1];
    const float bf0 = b4[HH + j0 + j2],     bf1 = b4[HH + j0 + j2 + 1];
    const float bg0 = b4[2 * HH + j0 + j2], bg1 = b4[2 * HH + j0 + j2 + 1];
    const float bo0 = b4[3 * HH + j0 + j2], bo1 = b4[3 * HH + j0 + j2 + 1];

    __syncthreads();

    // 4 accumulator chains: (nt 0/1) x (even/odd k-tile)
    f32x4 a0a = {0.f, 0.f, 0.f, 0.f}, a0b = a0a, a1a = a0a, a1b = a0a;
    f32x4 xr[8];   // x(t+1) prefetch registers

    // prologue: x-part of step 0 (direct loads)
#pragma unroll
    for (int kk = 0; kk < 4; kk++) {
        const f32x4* xp = (const f32x4*)(xrow + kk * 32 + lq * 8);
        short8v a_ = pack8(xp[0], xp[1]);
        if (kk & 1) { a0b = MF(a_, Bw[kk][0], a0b); a1b = MF(a_, Bw[kk][1], a1b); }
        else        { a0a = MF(a_, Bw[kk][0], a0a); a1a = MF(a_, Bw[kk][1], a1a); }
    }

    for (int t = 0; t < SS; t++) {
        const short* hcur = hbuf + (size_t)(t & 1) * (BB * HH);
        short* hnxt = hbuf + (size_t)((t + 1) & 1) * (BB * HH);

        // 1. merged poll+stage: each thread polls ITS producer's flag, then
        //    loads its 16 words (word column tid of rows 0..15) and writes
        //    them to LDS with the XOR swizzle. One barrier merges all.
        {
            if (!dead) {
                const unsigned e = (unsigned)t;
                int it = 0;
                while (__hip_atomic_load(myflag, __ATOMIC_RELAXED,
                                         __HIP_MEMORY_SCOPE_AGENT) < e) {
                    if (++it > SPIN_LIM) { dead = 1; break; }
                }
            }
            const unsigned long long* hsrc =
                (const unsigned long long*)(hcur + (size_t)m0 * HH);
            unsigned long long v[16];
#pragma unroll
            for (int q = 0; q < 16; q++)
                v[q] = __hip_atomic_load(hsrc + q * 256 + tid,
                                         __ATOMIC_RELAXED, __HIP_MEMORY_SCOPE_AGENT);
#pragma unroll
            for (int q = 0; q < 16; q++) {
                int off = (tid * 8) ^ ((q & 7) << 4);
                *(unsigned long long*)((char*)hstage + q * 2048 + off) = v[q];
            }
        }
        __syncthreads();

        // 2. h-part MFMAs: A-fragments from swizzled LDS (4 chains)
#pragma unroll
        for (int kk2 = 0; kk2 < 32; kk2++) {
            short8v a_ = *(const short8v*)((const char*)hstage + lr * 2048 +
                                           ((kk2 * 64 + lq * 16) ^ ((lr & 7) << 4)));
            if (kk2 & 1) { a0b = MF(a_, Bw[kk2 + 4][0], a0b); a1b = MF(a_, Bw[kk2 + 4][1], a1b); }
            else         { a0a = MF(a_, Bw[kk2 + 4][0], a0a); a1a = MF(a_, Bw[kk2 + 4][1], a1a); }
        }

        // 3. gates -> LDS   (C/D map: col = lane&15, row = lq*4 + r)
#pragma unroll
        for (int r = 0; r < 4; r++) {
            g4s[g][lq * 4 + r][lr]      = a0a[r] + a0b[r];
            g4s[g][lq * 4 + r][16 + lr] = a1a[r] + a1b[r];
        }
        __syncthreads();

        // 4. elementwise + h(t+1) store (relaxed agent atomic, tracked)
        {
            float gi0 = g4s[0][m_e][j2] + bi0, gi1 = g4s[0][m_e][j2 + 1] + bi1;
            float gf0 = g4s[1][m_e][j2] + bf0, gf1 = g4s[1][m_e][j2 + 1] + bf1;
            float gg0 = g4s[2][m_e][j2] + bg0, gg1 = g4s[2][m_e][j2 + 1] + bg1;
            float go0 = g4s[3][m_e][j2] + bo0, go1 = g4s[3][m_e][j2 + 1] + bo1;
            float si0 = 1.f / (1.f + __expf(-gi0)), si1 = 1.f / (1.f + __expf(-gi1));
            float sf0 = 1.f / (1.f + __expf(-gf0)), sf1 = 1.f / (1.f + __expf(-gf1));
            float tg0 = 1.f - 2.f / (__expf(2.f * gg0) + 1.f);
            float tg1 = 1.f - 2.f / (__expf(2.f * gg1) + 1.f);
            float so0 = 1.f / (1.f + __expf(-go0)), so1 = 1.f / (1.f + __expf(-go1));
            float cn0 = sf0 * c_lds[m_e][j2] + si0 * tg0;
            float cn1 = sf1 * c_lds[m_e][j2 + 1] + si1 * tg1;
            c_lds[m_e][j2] = cn0;
            c_lds[m_e][j2 + 1] = cn1;
            float h0 = so0 * (1.f - 2.f / (__expf(2.f * cn0) + 1.f));
            float h1 = so1 * (1.f - 2.f / (__expf(2.f * cn1) + 1.f));
            unsigned pv = f2bfu(h0) | (f2bfu(h1) << 16);
            unsigned* hp = (unsigned*)(hnxt + (size_t)(m0 + m_e) * HH + j0 + j2);
            __hip_atomic_store(hp, pv, __ATOMIC_RELAXED, __HIP_MEMORY_SCOPE_AGENT);
            if (t == SS - 1) {
                *(float2*)(hf + (size_t)(m0 + m_e) * HH + j0 + j2) = make_float2(h0, h1);
            }
        }

        if (t == SS - 1) break;

        // 4b. issue x(t+1) prefetch loads (h-independent, compiler-tracked;
        //     drain together with the h-stores at the barrier below)
        {
            const float* xt = xrow + (size_t)(t + 1) * II;
#pragma unroll
            for (int kk = 0; kk < 4; kk++) {
                xr[2 * kk]     = *(const f32x4*)(xt + kk * 32 + lq * 8);
                xr[2 * kk + 1] = *(const f32x4*)(xt + kk * 32 + lq * 8 + 4);
            }
        }

        // 5. publish h(t+1): __syncthreads drains all waves' tracked stores
        //    (vmcnt(0) before s_barrier), then relaxed flag store.
        __syncthreads();
        if (!dead && tid == 0)
            __hip_atomic_store(&gflags[jg], (unsigned)(t + 1),
                               __ATOMIC_RELAXED, __HIP_MEMORY_SCOPE_AGENT);

        // 6. x-part of step t+1 from prefetched registers
        a0a = f32x4{0.f, 0.f, 0.f, 0.f}; a0b = a0a; a1a = a0a; a1b = a0a;
#pragma unroll
        for (int kk = 0; kk < 4; kk++) {
            short8v a_ = pack8(xr[2 * kk], xr[2 * kk + 1]);
            if (kk & 1) { a0b = MF(a_, Bw[kk][0], a0b); a1b = MF(a_, Bw[kk][1], a1b); }
            else        { a0a = MF(a_, Bw[kk][0], a0a); a1a = MF(a_, Bw[kk][1], a1a); }
        }
    }

    (void)dead;
}

// ---------------------------------------------------------------------------
// out[b][o] = h[b] . W_out[o] + b_out[o].  grid 128 (b), block 256.
// ---------------------------------------------------------------------------
__global__ void final_linear(const float* __restrict__ hf, const float* __restrict__ Wout,
                             const float* __restrict__ bout, float* __restrict__ out) {
    __shared__ float hs[HH];
    const int b = blockIdx.x;
    for (int i = threadIdx.x; i < HH; i += 256) hs[i] = hf[(size_t)b * HH + i];
    __syncthreads();
    const int w = threadIdx.x >> 6, l = threadIdx.x & 63;
    for (int o = w; o < NC; o += 4) {
        float s = 0.f;
        const float* wr = Wout + (size_t)o * HH;
        for (int jj = l; jj < HH; jj += 64) s += hs[jj] * wr[jj];
#pragma unroll
        for (int d = 32; d > 0; d >>= 1) s += __shfl_down(s, d);
        if (l == 0) out[b * NC + o] = s + bout[o];
    }
}

extern "C" void kernel_launch(void* const* d_in, const int* in_sizes, int n_in,
                              void* d_out, int out_size, void* d_ws, size_t ws_size,
                              hipStream_t stream) {
    const float* x    = (const float*)d_in[0];
    const float* W_ii = (const float*)d_in[1];
    const float* W_hi = (const float*)d_in[2];
    const float* b_ii = (const float*)d_in[3];
    const float* W_if = (const float*)d_in[4];
    const float* W_hf = (const float*)d_in[5];
    const float* b_if = (const float*)d_in[6];
    const float* W_ig = (const float*)d_in[7];
    const float* W_hg = (const float*)d_in[8];
    const float* b_ig = (const float*)d_in[9];
    const float* W_io = (const float*)d_in[10];
    const float* W_ho = (const float*)d_in[11];
    const float* b_io = (const float*)d_in[12];
    const float* W_out = (const float*)d_in[13];
    const float* b_out = (const float*)d_in[14];

    char* ws = (char*)d_ws;
    short* Bt   = (short*)ws;                                  // 9,437,184 B
    float* b4   = (float*)(ws + 9437184);                      // 16,384 B
    short* hbuf = (short*)(ws + 9437184 + 16384);              // 524,288 B
    float* hf   = (float*)(ws + 9437184 + 16384 + 524288);     // 524,288 B
    unsigned* flags = (unsigned*)(ws + 9437184 + 16384 + 524288 + 524288); // 4,096 B

    prep_weights<<<dim3(36, 32, 4), dim3(32, 8), 0, stream>>>(
        W_ii, W_if, W_ig, W_io, W_hi, W_hf, W_hg, W_ho, Bt);
    prep_misc<<<512, 256, 0, stream>>>(b_ii, b_if, b_ig, b_io, b4, hbuf, flags);

    lstm_persist<<<NB, 256, 0, stream>>>(x, Bt, b4, hbuf, hf, flags);

    final_linear<<<BB, 256, 0, stream>>>(hf, W_out, b_out, (float*)d_out);
}